// Round 6
// baseline (194.894 us; speedup 1.0000x reference)
//
#include <hip/hip_runtime.h>
#include <hip/hip_bf16.h>

typedef __attribute__((ext_vector_type(8))) short short8;   // 8 bf16 = 16B
typedef __attribute__((ext_vector_type(4))) short short4v;  // 4 bf16 = 8B
typedef __attribute__((ext_vector_type(4))) float f32x4;

#define GAS(p) ((const __attribute__((address_space(1))) void*)(p))
#define LAS(p) ((__attribute__((address_space(3))) void*)(p))

__device__ __forceinline__ short f2bf_bits(float f) {
    __hip_bfloat16 h = __float2bfloat16(f);
    return *reinterpret_cast<short*>(&h);
}

// ---------------- fp32 -> bf16 conversion, all three tensors in one launch --
__global__ __launch_bounds__(256) void cvt_all(const float* __restrict__ x,
                                               const float* __restrict__ w1,
                                               const float* __restrict__ w2,
                                               short* __restrict__ dx,
                                               short* __restrict__ dw1,
                                               short* __restrict__ dw2) {
    constexpr int N1 = 4194304, N2 = 3145728;   // x, w_in; w_out = 1048576
    int i = (blockIdx.x * 256 + threadIdx.x) * 8;
    const float* src; short* dst; int j;
    if (i < N1)            { src = x;  dst = dx;  j = i; }
    else if (i < N1 + N2)  { src = w1; dst = dw1; j = i - N1; }
    else                   { src = w2; dst = dw2; j = i - N1 - N2; }
    float4 a = *reinterpret_cast<const float4*>(src + j);
    float4 b = *reinterpret_cast<const float4*>(src + j + 4);
    short8 o;
    o[0] = f2bf_bits(a.x); o[1] = f2bf_bits(a.y);
    o[2] = f2bf_bits(a.z); o[3] = f2bf_bits(a.w);
    o[4] = f2bf_bits(b.x); o[5] = f2bf_bits(b.y);
    o[6] = f2bf_bits(b.z); o[7] = f2bf_bits(b.w);
    *reinterpret_cast<short8*>(dst + j) = o;
}

// ---------------- QKV projection GEMM ----------------
// 1D grid 768, XCD-chunked. V is written DIRECTLY transposed ([bh][d][L]),
// eliminating the separate transpose_v kernel.
__global__ __launch_bounds__(256) void gemm_qkv(const __hip_bfloat16* __restrict__ A,
                                                const __hip_bfloat16* __restrict__ B,
                                                const float* __restrict__ bias,
                                                __hip_bfloat16* __restrict__ Qb,
                                                __hip_bfloat16* __restrict__ Kb,
                                                __hip_bfloat16* __restrict__ Vt) {
    constexpr int K = 1024;
    __shared__ __hip_bfloat16 smem[2][128 * 32 + 128 * 32];
    const int tid = threadIdx.x;
    const int lane = tid & 63, wid = tid >> 6;
    const int wr = wid >> 1, wc = wid & 1;
    const int lr = lane & 15, lg = lane >> 4;

    const int bid = blockIdx.x;
    const int xcd = bid & 7, w = bid >> 3;         // w in [0,96)
    const int bx = (xcd & 1) * 12 + (w % 12);      // [0,24)
    const int by = (xcd >> 1) * 8 + (w / 12);      // [0,32)
    const int m0 = by * 128;
    const int n0 = bx * 128;

    const f32x4 fz = {0.f, 0.f, 0.f, 0.f};
    f32x4 acc[4][4];
#pragma unroll
    for (int i = 0; i < 4; i++)
#pragma unroll
        for (int j = 0; j < 4; j++) acc[i][j] = fz;

    const char* Abase = (const char*)A + (size_t)m0 * K * 2;
    const char* Bbase = (const char*)B + (size_t)n0 * K * 2;

    auto stage = [&](int buf, int kt) {
        const int kb = kt * 64;
        char* sA = (char*)&smem[buf][0];
        char* sB = (char*)&smem[buf][128 * 32];
#pragma unroll
        for (int i = 0; i < 2; i++) {
            int o = i * 4096 + tid * 16;
            int row = o >> 6, cb = o & 63;
            __builtin_amdgcn_global_load_lds(GAS(Abase + (size_t)row * 2048 + kb + cb),
                                             LAS(sA + o), 16, 0, 0);
        }
#pragma unroll
        for (int i = 0; i < 2; i++) {
            int o = i * 4096 + tid * 16;
            int row = o >> 6, cb = o & 63;
            __builtin_amdgcn_global_load_lds(GAS(Bbase + (size_t)row * 2048 + kb + cb),
                                             LAS(sB + o), 16, 0, 0);
        }
    };

    stage(0, 0);
    __syncthreads();
    int buf = 0;
    constexpr int NT = K / 32;
    for (int kt = 0; kt < NT; ++kt) {
        if (kt + 1 < NT) stage(buf ^ 1, kt + 1);
        const __hip_bfloat16* sA = &smem[buf][0];
        const __hip_bfloat16* sB = &smem[buf][128 * 32];
        short8 a[4], b[4];
#pragma unroll
        for (int i = 0; i < 4; i++)
            a[i] = *reinterpret_cast<const short8*>(sA + (wr * 64 + i * 16 + lr) * 32 + lg * 8);
#pragma unroll
        for (int j = 0; j < 4; j++)
            b[j] = *reinterpret_cast<const short8*>(sB + (wc * 64 + j * 16 + lr) * 32 + lg * 8);
#pragma unroll
        for (int i = 0; i < 4; i++)
#pragma unroll
            for (int j = 0; j < 4; j++)
                acc[i][j] = __builtin_amdgcn_mfma_f32_16x16x32_bf16(a[i], b[j], acc[i][j], 0, 0, 0);
        __syncthreads();
        buf ^= 1;
    }

#pragma unroll
    for (int j = 0; j < 4; j++) {
        int e = n0 + wc * 64 + j * 16 + lr;
        float bv = bias[e];
        int sec = e >> 10;
        int el = e & 1023;
        int h = el >> 6, d = el & 63;
        // Q carries 1/sqrt(64) * log2(e) so attention can use exp2 directly
        float scale = (sec == 0) ? 0.18033688011112042f : 1.0f;
#pragma unroll
        for (int i = 0; i < 4; i++) {
            int mb = m0 + wr * 64 + i * 16 + lg * 4;
#pragma unroll
            for (int r = 0; r < 4; r++) {
                int tok = mb + r;
                int bb = tok >> 11, l = tok & 2047;
                float v = (acc[i][j][r] + bv) * scale;
                __hip_bfloat16 hv = __float2bfloat16(v);
                int bh = bb * 16 + h;
                if (sec == 0)      Qb[((size_t)bh * 2048 + l) * 64 + d] = hv;
                else if (sec == 1) Kb[((size_t)bh * 2048 + l) * 64 + d] = hv;
                else               Vt[((size_t)bh * 64 + d) * 2048 + l] = hv;
            }
        }
    }
}

// ---------------- causal flash attention (2 q-tiles per block) ----------------
// 512 blocks, XCD-pinned (bid&7=XCD, 4 bh per XCD). Each block owns q-tile pair
// (qtA,qtB)=(30-2p,31-2p), longest first. One K/V stage feeds BOTH tiles'
// MFMAs (K/V fragments loaded once, used twice) -> LDS reads per unit work
// ~-40%, staging/barriers per unit work halved, 2 independent chains/wave.
// P buffers XOR-swizzled (no pad). LDS = 48KB -> 3 blocks/CU.
__global__ __launch_bounds__(256, 3) void attn(const __hip_bfloat16* __restrict__ Qg,
                                               const __hip_bfloat16* __restrict__ Kg,
                                               const __hip_bfloat16* __restrict__ Vtg,
                                               __hip_bfloat16* __restrict__ ctx) {
    const int bid = blockIdx.x;
    const int xcd = bid & 7, seq = bid >> 3;       // seq in [0,64)
    const int bh = (xcd << 2) | (seq & 3);         // 4 bh per XCD
    const int p = seq >> 2;                        // pair idx [0,16), ascending = longest first
    const int qtA = 30 - 2 * p, qtB = 31 - 2 * p;
    const int NT = qtB + 1;
    const int tid = threadIdx.x, lane = tid & 63, wq = tid >> 6;
    const int lr = lane & 15, lg = lane >> 4;

    __shared__ short Ks[2][64 * 64];     // [kv][d], swizzled 16B slots
    __shared__ short Vs[2][64 * 64];     // [d][kv], swizzled 16B slots
    __shared__ short Ps[2][4][16 * 64];  // [tile][wave][q][kv], XOR-swizzled

    const char* kbase = (const char*)Kg + (size_t)bh * (2048 * 64 * 2);
    const char* vbase = (const char*)Vtg + (size_t)bh * (64 * 2048 * 2);
    const int bb = bh >> 4, h = bh & 15;

    // staging addressing (pre-swizzled global source, linear LDS dest)
    const int srow = tid >> 3;
    const int ssl = (tid & 7) ^ (srow & 7);
    const char* gk0 = kbase + srow * 128 + ssl * 16;          // += kt*8192
    const char* gv0 = vbase + (size_t)srow * 4096 + ssl * 16; // += kt*128

    // fragment-read byte offsets (slot = lg^(lr&7) invariant across n)
    const int kfA = lr * 128 + ((lg ^ (lr & 7)) * 16);        // + n*2048
    const int kfB = lr * 128 + (((4 + lg) ^ (lr & 7)) * 16);
    // P-buffer swizzled offsets
    const int sw = (lr & 7) << 4;
    char* pbA = (char*)&Ps[0][wq][0];
    char* pbB = (char*)&Ps[1][wq][0];
    const int prd0 = lr * 128 + ((lg * 16) ^ sw);
    const int prd1 = lr * 128 + ((64 + lg * 16) ^ sw);

    auto stage = [&](int buf, int kt) {
        char* dK = (char*)&Ks[buf][0] + tid * 16;
        char* dV = (char*)&Vs[buf][0] + tid * 16;
        const char* srcK = gk0 + (size_t)kt * 8192;
        const char* srcV = gv0 + (size_t)kt * 128;
        __builtin_amdgcn_global_load_lds(GAS(srcK), LAS(dK), 16, 0, 0);
        __builtin_amdgcn_global_load_lds(GAS(srcK + 4096), LAS(dK + 4096), 16, 0, 0);
        __builtin_amdgcn_global_load_lds(GAS(srcV), LAS(dV), 16, 0, 0);
        __builtin_amdgcn_global_load_lds(GAS(srcV + 131072), LAS(dV + 4096), 16, 0, 0);
    };

    // softmax + pack + LDS write for one tile (s indexed by constants only)
    auto smpack = [&](f32x4* s, f32x4* o, float& m, float& ls, char* pb) {
        float mx = fmaxf(fmaxf(fmaxf(s[0][0], s[0][1]), fmaxf(s[0][2], s[0][3])),
                         fmaxf(fmaxf(fmaxf(s[1][0], s[1][1]), fmaxf(s[1][2], s[1][3])),
                               fmaxf(fmaxf(fmaxf(s[2][0], s[2][1]), fmaxf(s[2][2], s[2][3])),
                                     fmaxf(fmaxf(s[3][0], s[3][1]), fmaxf(s[3][2], s[3][3])))));
        mx = fmaxf(mx, __shfl_xor(mx, 16));
        mx = fmaxf(mx, __shfl_xor(mx, 32));
        if (!__all(mx - m <= 11.54f)) {
            float mnew = fmaxf(m, mx);
            float corr = __builtin_amdgcn_exp2f(m - mnew);
            m = mnew;
            ls *= corr;
            float c0 = __shfl(corr, (lane & 48) | (lg * 4 + 0));
            float c1 = __shfl(corr, (lane & 48) | (lg * 4 + 1));
            float c2 = __shfl(corr, (lane & 48) | (lg * 4 + 2));
            float c3 = __shfl(corr, (lane & 48) | (lg * 4 + 3));
#pragma unroll
            for (int n = 0; n < 4; n++) {
                o[n][0] *= c0; o[n][1] *= c1; o[n][2] *= c2; o[n][3] *= c3;
            }
        }
        float psum = 0.f;
#pragma unroll
        for (int n = 0; n < 4; n++) {
            float p0 = __builtin_amdgcn_exp2f(s[n][0] - m);
            float p1 = __builtin_amdgcn_exp2f(s[n][1] - m);
            float p2 = __builtin_amdgcn_exp2f(s[n][2] - m);
            float p3 = __builtin_amdgcn_exp2f(s[n][3] - m);
            s[n][0] = p0; s[n][1] = p1; s[n][2] = p2; s[n][3] = p3;
            psum += (p0 + p1) + (p2 + p3);
        }
        ls += psum;
#pragma unroll
        for (int n = 0; n < 4; n++) {
            short4v pk;
            pk[0] = f2bf_bits(s[n][0]); pk[1] = f2bf_bits(s[n][1]);
            pk[2] = f2bf_bits(s[n][2]); pk[3] = f2bf_bits(s[n][3]);
            *reinterpret_cast<short4v*>(pb + lr * 128 + (((n * 32 + lg * 8) ^ sw))) = pk;
        }
    };

    const f32x4 fz = {0.f, 0.f, 0.f, 0.f};
    const int qbA = qtA * 64 + wq * 16;
    const int qbB = qtB * 64 + wq * 16;

    const __hip_bfloat16* QrA = Qg + ((size_t)bh * 2048 + qbA + lr) * 64 + lg * 8;
    const __hip_bfloat16* QrB = Qg + ((size_t)bh * 2048 + qbB + lr) * 64 + lg * 8;
    short8 qA0 = *reinterpret_cast<const short8*>(QrA);
    short8 qA1 = *reinterpret_cast<const short8*>(QrA + 32);
    short8 qB0 = *reinterpret_cast<const short8*>(QrB);
    short8 qB1 = *reinterpret_cast<const short8*>(QrB + 32);

    f32x4 oA[4], oB[4];
#pragma unroll
    for (int n = 0; n < 4; n++) { oA[n] = fz; oB[n] = fz; }
    float mA = -1e30f, mB = -1e30f, lsA = 0.f, lsB = 0.f;

    stage(0, 0);
    __syncthreads();
    int buf = 0;
#pragma unroll 1
    for (int kt = 0; kt < NT - 1; ++kt) {
        stage(buf ^ 1, kt + 1);
        const char* sK = (const char*)&Ks[buf][0];
        const char* sV = (const char*)&Vs[buf][0];

        // QK^T for both tiles; K fragments loaded ONCE, used twice
        f32x4 sA[4], sB[4];
#pragma unroll
        for (int n = 0; n < 4; n++) { sA[n] = fz; sB[n] = fz; }
        __builtin_amdgcn_s_setprio(1);
#pragma unroll
        for (int n = 0; n < 4; n++) {
            short8 k0 = *reinterpret_cast<const short8*>(sK + kfA + n * 2048);
            short8 k1 = *reinterpret_cast<const short8*>(sK + kfB + n * 2048);
            sB[n] = __builtin_amdgcn_mfma_f32_16x16x32_bf16(k0, qB0, sB[n], 0, 0, 0);
            sB[n] = __builtin_amdgcn_mfma_f32_16x16x32_bf16(k1, qB1, sB[n], 0, 0, 0);
            sA[n] = __builtin_amdgcn_mfma_f32_16x16x32_bf16(k0, qA0, sA[n], 0, 0, 0);
            sA[n] = __builtin_amdgcn_mfma_f32_16x16x32_bf16(k1, qA1, sA[n], 0, 0, 0);
        }
        __builtin_amdgcn_s_setprio(0);

        if (kt == NT - 2) {   // tile A diagonal
            int q = qbA + lr;
#pragma unroll
            for (int n = 0; n < 4; n++) {
                int kvb = kt * 64 + n * 16 + lg * 4;
#pragma unroll
                for (int r = 0; r < 4; r++)
                    if (kvb + r > q) sA[n][r] = -1e30f;
            }
        }

        smpack(sB, oB, mB, lsB, pbB);
        smpack(sA, oA, mA, lsA, pbA);
        asm volatile("s_waitcnt lgkmcnt(0)" ::: "memory");
        short8 paA0 = *reinterpret_cast<const short8*>(pbA + prd0);
        short8 paA1 = *reinterpret_cast<const short8*>(pbA + prd1);
        short8 paB0 = *reinterpret_cast<const short8*>(pbB + prd0);
        short8 paB1 = *reinterpret_cast<const short8*>(pbB + prd1);

        // PV for both tiles; V fragments loaded ONCE, used twice
        __builtin_amdgcn_s_setprio(1);
#pragma unroll
        for (int n = 0; n < 4; n++) {
            short8 vf0 = *reinterpret_cast<const short8*>(sV + kfA + n * 2048);
            short8 vf1 = *reinterpret_cast<const short8*>(sV + kfB + n * 2048);
            oB[n] = __builtin_amdgcn_mfma_f32_16x16x32_bf16(paB0, vf0, oB[n], 0, 0, 0);
            oB[n] = __builtin_amdgcn_mfma_f32_16x16x32_bf16(paB1, vf1, oB[n], 0, 0, 0);
            oA[n] = __builtin_amdgcn_mfma_f32_16x16x32_bf16(paA0, vf0, oA[n], 0, 0, 0);
            oA[n] = __builtin_amdgcn_mfma_f32_16x16x32_bf16(paA1, vf1, oA[n], 0, 0, 0);
        }
        __builtin_amdgcn_s_setprio(0);
        __syncthreads();
        buf ^= 1;
    }

    // tail iteration kt = NT-1: tile B only, with diagonal mask
    {
        const int kt = NT - 1;
        const char* sK = (const char*)&Ks[buf][0];
        const char* sV = (const char*)&Vs[buf][0];
        f32x4 sB[4];
#pragma unroll
        for (int n = 0; n < 4; n++) sB[n] = fz;
        __builtin_amdgcn_s_setprio(1);
#pragma unroll
        for (int n = 0; n < 4; n++) {
            short8 k0 = *reinterpret_cast<const short8*>(sK + kfA + n * 2048);
            short8 k1 = *reinterpret_cast<const short8*>(sK + kfB + n * 2048);
            sB[n] = __builtin_amdgcn_mfma_f32_16x16x32_bf16(k0, qB0, sB[n], 0, 0, 0);
            sB[n] = __builtin_amdgcn_mfma_f32_16x16x32_bf16(k1, qB1, sB[n], 0, 0, 0);
        }
        __builtin_amdgcn_s_setprio(0);
        int q = qbB + lr;
#pragma unroll
        for (int n = 0; n < 4; n++) {
            int kvb = kt * 64 + n * 16 + lg * 4;
#pragma unroll
            for (int r = 0; r < 4; r++)
                if (kvb + r > q) sB[n][r] = -1e30f;
        }
        smpack(sB, oB, mB, lsB, pbB);
        asm volatile("s_waitcnt lgkmcnt(0)" ::: "memory");
        short8 paB0 = *reinterpret_cast<const short8*>(pbB + prd0);
        short8 paB1 = *reinterpret_cast<const short8*>(pbB + prd1);
        __builtin_amdgcn_s_setprio(1);
#pragma unroll
        for (int n = 0; n < 4; n++) {
            short8 vf0 = *reinterpret_cast<const short8*>(sV + kfA + n * 2048);
            short8 vf1 = *reinterpret_cast<const short8*>(sV + kfB + n * 2048);
            oB[n] = __builtin_amdgcn_mfma_f32_16x16x32_bf16(paB0, vf0, oB[n], 0, 0, 0);
            oB[n] = __builtin_amdgcn_mfma_f32_16x16x32_bf16(paB1, vf1, oB[n], 0, 0, 0);
        }
        __builtin_amdgcn_s_setprio(0);
    }

    // epilogue: finish row-sums, normalize, store both tiles
    lsA += __shfl_xor(lsA, 16); lsA += __shfl_xor(lsA, 32);
    lsB += __shfl_xor(lsB, 16); lsB += __shfl_xor(lsB, 32);
#pragma unroll 1
    for (int t = 0; t < 2; ++t) {
        float ls = t ? lsB : lsA;
        int qb = t ? qbB : qbA;
        f32x4* o = t ? oB : oA;
        float l0 = __shfl(ls, (lane & 48) | (lg * 4 + 0));
        float l1 = __shfl(ls, (lane & 48) | (lg * 4 + 1));
        float l2 = __shfl(ls, (lane & 48) | (lg * 4 + 2));
        float l3 = __shfl(ls, (lane & 48) | (lg * 4 + 3));
        float inv[4] = {1.0f / l0, 1.0f / l1, 1.0f / l2, 1.0f / l3};
#pragma unroll
        for (int r = 0; r < 4; r++) {
            int tok = qb + lg * 4 + r;
            __hip_bfloat16* crow = ctx + ((size_t)(bb * 2048 + tok)) * 1024 + h * 64;
#pragma unroll
            for (int n = 0; n < 4; n++) crow[n * 16 + lr] = __float2bfloat16(o[n][r] * inv[r]);
        }
    }
}

// ---------------- output projection GEMM (128x64 tile) ----------------
// 1D grid 512, XCD-chunked: per XCD 16(bx) x 4(by) -> ~3MB L2 working set.
__global__ __launch_bounds__(256) void gemm_out(const __hip_bfloat16* __restrict__ A,
                                                const __hip_bfloat16* __restrict__ B,
                                                const float* __restrict__ bias,
                                                float* __restrict__ out) {
    constexpr int K = 1024;
    __shared__ __hip_bfloat16 smem[2][128 * 32 + 64 * 32];
    const int tid = threadIdx.x;
    const int lane = tid & 63, wid = tid >> 6;
    const int wr = wid >> 1, wc = wid & 1;
    const int lr = lane & 15, lg = lane >> 4;

    const int bid = blockIdx.x;
    const int xcd = bid & 7, w = bid >> 3;     // w in [0,64)
    const int bx = w & 15;                     // [0,16)
    const int by = (xcd << 2) | (w >> 4);      // [0,32)
    const int m0 = by * 128;
    const int n0 = bx * 64;

    const f32x4 fz = {0.f, 0.f, 0.f, 0.f};
    f32x4 acc[4][2];
#pragma unroll
    for (int i = 0; i < 4; i++)
#pragma unroll
        for (int j = 0; j < 2; j++) acc[i][j] = fz;

    const char* Abase = (const char*)A + (size_t)m0 * K * 2;
    const char* Bbase = (const char*)B + (size_t)n0 * K * 2;

    auto stage = [&](int buf, int kt) {
        const int kb = kt * 64;
        char* sA = (char*)&smem[buf][0];
        char* sB = (char*)&smem[buf][128 * 32];
#pragma unroll
        for (int i = 0; i < 2; i++) {
            int o = i * 4096 + tid * 16;
            int row = o >> 6, cb = o & 63;
            __builtin_amdgcn_global_load_lds(GAS(Abase + (size_t)row * 2048 + kb + cb),
                                             LAS(sA + o), 16, 0, 0);
        }
        {
            int o = tid * 16;
            int row = o >> 6, cb = o & 63;
            __builtin_amdgcn_global_load_lds(GAS(Bbase + (size_t)row * 2048 + kb + cb),
                                             LAS(sB + o), 16, 0, 0);
        }
    };

    stage(0, 0);
    __syncthreads();
    int buf = 0;
    constexpr int NT = K / 32;
    for (int kt = 0; kt < NT; ++kt) {
        if (kt + 1 < NT) stage(buf ^ 1, kt + 1);
        const __hip_bfloat16* sA = &smem[buf][0];
        const __hip_bfloat16* sB = &smem[buf][128 * 32];
        short8 a[4], b[2];
#pragma unroll
        for (int i = 0; i < 4; i++)
            a[i] = *reinterpret_cast<const short8*>(sA + (wr * 64 + i * 16 + lr) * 32 + lg * 8);
#pragma unroll
        for (int j = 0; j < 2; j++)
            b[j] = *reinterpret_cast<const short8*>(sB + (wc * 32 + j * 16 + lr) * 32 + lg * 8);
#pragma unroll
        for (int i = 0; i < 4; i++)
#pragma unroll
            for (int j = 0; j < 2; j++)
                acc[i][j] = __builtin_amdgcn_mfma_f32_16x16x32_bf16(a[i], b[j], acc[i][j], 0, 0, 0);
        __syncthreads();
        buf ^= 1;
    }

#pragma unroll
    for (int j = 0; j < 2; j++) {
        int e = n0 + wc * 32 + j * 16 + lr;
        float bv = bias[e];
#pragma unroll
        for (int i = 0; i < 4; i++) {
            int mb = m0 + wr * 64 + i * 16 + lg * 4;
#pragma unroll
            for (int r = 0; r < 4; r++) {
                out[(size_t)(mb + r) * 1024 + e] = acc[i][j][r] + bv;
            }
        }
    }
}

extern "C" void kernel_launch(void* const* d_in, const int* in_sizes, int n_in,
                              void* d_out, int out_size, void* d_ws, size_t ws_size,
                              hipStream_t stream) {
    const float* x = (const float*)d_in[0];
    const float* w_in = (const float*)d_in[1];
    const float* b_in = (const float*)d_in[2];
    const float* w_out = (const float*)d_in[3];
    const float* b_out = (const float*)d_in[4];
    float* out = (float*)d_out;

    char* ws = (char*)d_ws;
    __hip_bfloat16* xbf  = (__hip_bfloat16*)(ws);
    __hip_bfloat16* wbf  = (__hip_bfloat16*)(ws + (8ull << 20));
    __hip_bfloat16* owbf = (__hip_bfloat16*)(ws + (14ull << 20));
    __hip_bfloat16* Qb   = (__hip_bfloat16*)(ws + (16ull << 20));
    __hip_bfloat16* Kb   = (__hip_bfloat16*)(ws + (24ull << 20));
    __hip_bfloat16* Vt   = (__hip_bfloat16*)(ws + (40ull << 20));
    __hip_bfloat16* ctxb = (__hip_bfloat16*)(ws + (48ull << 20));

    cvt_all<<<4096, 256, 0, stream>>>(x, w_in, w_out, (short*)xbf, (short*)wbf, (short*)owbf);
    gemm_qkv<<<768, 256, 0, stream>>>(xbf, wbf, b_in, Qb, Kb, Vt);
    attn<<<512, 256, 0, stream>>>(Qb, Kb, Vt, ctxb);
    gemm_out<<<512, 256, 0, stream>>>(ctxb, owbf, b_out, out);
}